// Round 1
// baseline (443.481 us; speedup 1.0000x reference)
//
#include <hip/hip_runtime.h>

// -------------------------------------------------------------------------
// GCN: h1 = relu(Agg(x@W1)+b1); h2 = relu(Agg(h1@W2)+b2); out = h2@Wl+bl
// Agg(t)[i] = dinv[i]^2 * t[i] + sum_{e: dst=i} dinv[src]*dinv[i] * t[src]
// deg[i] = 1 + in_degree(i); dinv = rsqrt(deg)
// Strategy: build dst-sorted CSR per call (no scatter atomics in hot loop),
// per-node gather aggregation, simple LDS-tiled fp32 GEMMs.
// -------------------------------------------------------------------------

__global__ void k_zero_i32(int* __restrict__ p, int n) {
  int i = blockIdx.x * blockDim.x + threadIdx.x;
  if (i < n) p[i] = 0;
}

__global__ void k_count(const int* __restrict__ dst, int E, int* __restrict__ cnt) {
  int i = blockIdx.x * blockDim.x + threadIdx.x;
  if (i < E) atomicAdd(&cnt[dst[i]], 1);
}

// per-256-chunk sums
__global__ void k_scan1(const int* __restrict__ cnt, int n, int* __restrict__ partial) {
  __shared__ int s[256];
  int i = blockIdx.x * 256 + threadIdx.x;
  s[threadIdx.x] = (i < n) ? cnt[i] : 0;
  __syncthreads();
  for (int off = 128; off > 0; off >>= 1) {
    if (threadIdx.x < off) s[threadIdx.x] += s[threadIdx.x + off];
    __syncthreads();
  }
  if (threadIdx.x == 0) partial[blockIdx.x] = s[0];
}

// exclusive scan of up to 256 partials (single block)
__global__ void k_scan2(int* __restrict__ partial, int nb) {
  __shared__ int s[256];
  int t = threadIdx.x;
  int v = (t < nb) ? partial[t] : 0;
  s[t] = v;
  __syncthreads();
  for (int off = 1; off < 256; off <<= 1) {
    int u = (t >= off) ? s[t - off] : 0;
    __syncthreads();
    s[t] += u;
    __syncthreads();
  }
  if (t < nb) partial[t] = s[t] - v;  // exclusive
}

// row offsets + cursor + dinv
__global__ void k_scan3(const int* __restrict__ cnt, const int* __restrict__ partial,
                        int n, int* __restrict__ row_off, int* __restrict__ cursor,
                        float* __restrict__ dinv) {
  __shared__ int s[256];
  int t = threadIdx.x;
  int i = blockIdx.x * 256 + t;
  int v = (i < n) ? cnt[i] : 0;
  s[t] = v;
  __syncthreads();
  for (int off = 1; off < 256; off <<= 1) {
    int u = (t >= off) ? s[t - off] : 0;
    __syncthreads();
    s[t] += u;
    __syncthreads();
  }
  int incl = s[t];
  int excl = incl - v;
  int base = partial[blockIdx.x];
  if (i < n) {
    row_off[i] = base + excl;
    cursor[i] = base + excl;
    dinv[i] = rsqrtf((float)(v + 1));
    if (i == n - 1) row_off[n] = base + incl;
  }
}

__global__ void k_place(const int* __restrict__ src, const int* __restrict__ dst, int E,
                        int* __restrict__ cursor, const float* __restrict__ dinv,
                        int* __restrict__ csr_src, float* __restrict__ csr_norm) {
  int e = blockIdx.x * blockDim.x + threadIdx.x;
  if (e < E) {
    int s = src[e], d = dst[e];
    int pos = atomicAdd(&cursor[d], 1);
    csr_src[pos] = s;
    csr_norm[pos] = dinv[s] * dinv[d];
  }
}

// C[M x BN] = A[M x 128] @ B[128 x BN] (+ bias). BM=64, BK=32, 256 threads.
template <int BN, int TM, int TN, int CT>
__global__ void gemm_k128(const float* __restrict__ A, const float* __restrict__ B,
                          const float* __restrict__ bias, float* __restrict__ C, int M) {
  constexpr int K = 128, BK = 32, BM = 64;
  __shared__ float As[BM][BK + 1];
  __shared__ float Bs[BK][BN];
  int t = threadIdx.x;
  int tx = t % CT;        // column group
  int ty = t / CT;        // row group
  int row0 = blockIdx.x * BM;
  float acc[TM][TN] = {};
  for (int k0 = 0; k0 < K; k0 += BK) {
    for (int l = t; l < BM * BK; l += 256) {
      int r = l / BK, c = l % BK;
      int gr = row0 + r;
      As[r][c] = (gr < M) ? A[(size_t)gr * K + k0 + c] : 0.f;
    }
    for (int l = t; l < BK * BN; l += 256) {
      int r = l / BN, c = l % BN;
      Bs[r][c] = B[(size_t)(k0 + r) * BN + c];
    }
    __syncthreads();
#pragma unroll
    for (int kk = 0; kk < BK; ++kk) {
      float b[TN];
#pragma unroll
      for (int j = 0; j < TN; ++j) b[j] = Bs[kk][tx * TN + j];
#pragma unroll
      for (int i = 0; i < TM; ++i) {
        float a = As[ty * TM + i][kk];
#pragma unroll
        for (int j = 0; j < TN; ++j) acc[i][j] += a * b[j];
      }
    }
    __syncthreads();
  }
#pragma unroll
  for (int i = 0; i < TM; ++i) {
    int r = row0 + ty * TM + i;
    if (r < M) {
#pragma unroll
      for (int j = 0; j < TN; ++j) {
        int c = tx * TN + j;
        float v = acc[i][j];
        if (bias) v += bias[c];
        C[(size_t)r * BN + c] = v;
      }
    }
  }
}

// one wave per node; lane handles 2 features (float2). D=128 fixed.
__global__ void k_agg(const float* __restrict__ t, const int* __restrict__ row_off,
                      const int* __restrict__ csr_src, const float* __restrict__ csr_norm,
                      const float* __restrict__ dinv, const float* __restrict__ bias,
                      float* __restrict__ out, int n) {
  int wave = threadIdx.x >> 6;
  int lane = threadIdx.x & 63;
  int node = blockIdx.x * 4 + wave;
  if (node >= n) return;
  float di = dinv[node];
  float self = di * di;
  float2 v = ((const float2*)(t + (size_t)node * 128))[lane];
  float2 acc = make_float2(self * v.x, self * v.y);
  int e0 = row_off[node], e1 = row_off[node + 1];
  for (int e = e0; e < e1; ++e) {
    int s = csr_src[e];
    float w = csr_norm[e];
    float2 u = ((const float2*)(t + (size_t)s * 128))[lane];
    acc.x += w * u.x;
    acc.y += w * u.y;
  }
  float2 bb = ((const float2*)bias)[lane];
  acc.x = fmaxf(acc.x + bb.x, 0.f);
  acc.y = fmaxf(acc.y + bb.y, 0.f);
  ((float2*)(out + (size_t)node * 128))[lane] = acc;
}

extern "C" void kernel_launch(void* const* d_in, const int* in_sizes, int n_in,
                              void* d_out, int out_size, void* d_ws, size_t ws_size,
                              hipStream_t stream) {
  const float* x  = (const float*)d_in[0];
  const int*   ei = (const int*)d_in[1];
  const float* W1 = (const float*)d_in[2];
  const float* b1 = (const float*)d_in[3];
  const float* W2 = (const float*)d_in[4];
  const float* b2 = (const float*)d_in[5];
  const float* Wl = (const float*)d_in[6];
  const float* bl = (const float*)d_in[7];
  float* out = (float*)d_out;

  const int D = 128;
  int N = in_sizes[0] / D;
  int E = in_sizes[1] / 2;
  const int* src = ei;
  const int* dst = ei + E;

  // workspace layout
  char* ws = (char*)d_ws;
  float* t_buf = (float*)ws;  ws += (size_t)N * D * sizeof(float);
  float* g_buf = (float*)ws;  ws += (size_t)N * D * sizeof(float);
  int* cnt     = (int*)ws;    ws += (size_t)N * sizeof(int);
  int* row_off = (int*)ws;    ws += ((size_t)N + 1) * sizeof(int);
  int* cursor  = (int*)ws;    ws += (size_t)N * sizeof(int);
  float* dinv  = (float*)ws;  ws += (size_t)N * sizeof(float);
  int* partial = (int*)ws;    ws += 256 * sizeof(int);
  int* csr_src = (int*)ws;    ws += (size_t)E * sizeof(int);
  float* csr_norm = (float*)ws;

  int nb_n = (N + 255) / 256;   // 196 for N=50000 (fits single-block scan2)
  int nb_e = (E + 255) / 256;

  // ---- graph preprocessing ----
  k_zero_i32<<<nb_n, 256, 0, stream>>>(cnt, N);
  k_count<<<nb_e, 256, 0, stream>>>(dst, E, cnt);
  k_scan1<<<nb_n, 256, 0, stream>>>(cnt, N, partial);
  k_scan2<<<1, 256, 0, stream>>>(partial, nb_n);
  k_scan3<<<nb_n, 256, 0, stream>>>(cnt, partial, N, row_off, cursor, dinv);
  k_place<<<nb_e, 256, 0, stream>>>(src, dst, E, cursor, dinv, csr_src, csr_norm);

  int gemm_blocks = (N + 63) / 64;
  int agg_blocks = (N + 3) / 4;

  // ---- layer 1 ----
  gemm_k128<128, 8, 4, 32><<<gemm_blocks, 256, 0, stream>>>(x, W1, nullptr, t_buf, N);
  k_agg<<<agg_blocks, 256, 0, stream>>>(t_buf, row_off, csr_src, csr_norm, dinv, b1, g_buf, N);
  // ---- layer 2 ----
  gemm_k128<128, 8, 4, 32><<<gemm_blocks, 256, 0, stream>>>(g_buf, W2, nullptr, t_buf, N);
  k_agg<<<agg_blocks, 256, 0, stream>>>(t_buf, row_off, csr_src, csr_norm, dinv, b2, g_buf, N);
  // ---- classifier ----
  gemm_k128<64, 4, 4, 16><<<gemm_blocks, 256, 0, stream>>>(g_buf, Wl, bl, out, N);
}

// Round 2
// 343.173 us; speedup vs baseline: 1.2923x; 1.2923x over previous
//
#include <hip/hip_runtime.h>

// -------------------------------------------------------------------------
// GCN: h1 = relu(Agg(x@W1)+b1); h2 = relu(Agg(h1@W2)+b2); out = h2@Wl+bl
// Agg(t)[i] = dinv[i]^2 * t[i] + sum_{e: dst=i} dinv[src]*dinv[i] * t[src]
// R2: fp32 GEMM rewritten (float4 LDS, 4x8 thread tile, ds_read_b128);
//     agg edge-loop unrolled x4 for gather MLP.
// -------------------------------------------------------------------------

__global__ void k_zero_i32(int* __restrict__ p, int n) {
  int i = blockIdx.x * blockDim.x + threadIdx.x;
  if (i < n) p[i] = 0;
}

__global__ void k_count(const int* __restrict__ dst, int E, int* __restrict__ cnt) {
  int i = blockIdx.x * blockDim.x + threadIdx.x;
  if (i < E) atomicAdd(&cnt[dst[i]], 1);
}

__global__ void k_scan1(const int* __restrict__ cnt, int n, int* __restrict__ partial) {
  __shared__ int s[256];
  int i = blockIdx.x * 256 + threadIdx.x;
  s[threadIdx.x] = (i < n) ? cnt[i] : 0;
  __syncthreads();
  for (int off = 128; off > 0; off >>= 1) {
    if (threadIdx.x < off) s[threadIdx.x] += s[threadIdx.x + off];
    __syncthreads();
  }
  if (threadIdx.x == 0) partial[blockIdx.x] = s[0];
}

__global__ void k_scan2(int* __restrict__ partial, int nb) {
  __shared__ int s[256];
  int t = threadIdx.x;
  int v = (t < nb) ? partial[t] : 0;
  s[t] = v;
  __syncthreads();
  for (int off = 1; off < 256; off <<= 1) {
    int u = (t >= off) ? s[t - off] : 0;
    __syncthreads();
    s[t] += u;
    __syncthreads();
  }
  if (t < nb) partial[t] = s[t] - v;  // exclusive
}

__global__ void k_scan3(const int* __restrict__ cnt, const int* __restrict__ partial,
                        int n, int* __restrict__ row_off, int* __restrict__ cursor,
                        float* __restrict__ dinv) {
  __shared__ int s[256];
  int t = threadIdx.x;
  int i = blockIdx.x * 256 + t;
  int v = (i < n) ? cnt[i] : 0;
  s[t] = v;
  __syncthreads();
  for (int off = 1; off < 256; off <<= 1) {
    int u = (t >= off) ? s[t - off] : 0;
    __syncthreads();
    s[t] += u;
    __syncthreads();
  }
  int incl = s[t];
  int excl = incl - v;
  int base = partial[blockIdx.x];
  if (i < n) {
    row_off[i] = base + excl;
    cursor[i] = base + excl;
    dinv[i] = rsqrtf((float)(v + 1));
    if (i == n - 1) row_off[n] = base + incl;
  }
}

__global__ void k_place(const int* __restrict__ src, const int* __restrict__ dst, int E,
                        int* __restrict__ cursor, const float* __restrict__ dinv,
                        int* __restrict__ csr_src, float* __restrict__ csr_norm) {
  int e = blockIdx.x * blockDim.x + threadIdx.x;
  if (e < E) {
    int s = src[e], d = dst[e];
    int pos = atomicAdd(&cursor[d], 1);
    csr_src[pos] = s;
    csr_norm[pos] = dinv[s] * dinv[d];
  }
}

// ------------------- fp32 GEMM v2 -------------------
// C[M x BN] = A[M x 128] @ B[128 x BN] (+bias). BM=64, BK=16, 256 thr.
// Thread grid 16(tx) x 16(ty): per-thread tile TM=4 rows x TN cols.
// All LDS accesses are 16B-aligned float4.
template <int BN, int TN>
__global__ __launch_bounds__(256) void gemm_v2(const float* __restrict__ A,
                                               const float* __restrict__ B,
                                               const float* __restrict__ bias,
                                               float* __restrict__ C, int M) {
  constexpr int K = 128, BK = 16, BM = 64;
  __shared__ float As[BK][BM + 4];   // [k][m], stride 68 floats = 272B (16B-mult)
  __shared__ float Bs[BK][BN + 4];   // [k][n], stride BN+4 (132 or 68) -> 16B-mult
  int t = threadIdx.x;
  int tx = t & 15;        // column group
  int ty = t >> 4;        // row group
  int row0 = blockIdx.x * BM;

  float acc[4][TN] = {};

  // A-staging indices: t -> (m = t/4, kq = t%4), one float4 per thread per tile
  int am = t >> 2;
  int akq = (t & 3) * 4;

  for (int k0 = 0; k0 < K; k0 += BK) {
    // stage A (64x16): transposed store As[k][m]
    {
      int gr = row0 + am;
      float4 v = make_float4(0.f, 0.f, 0.f, 0.f);
      if (gr < M) v = *(const float4*)&A[(size_t)gr * K + k0 + akq];
      As[akq + 0][am] = v.x;
      As[akq + 1][am] = v.y;
      As[akq + 2][am] = v.z;
      As[akq + 3][am] = v.w;
    }
    // stage B (16 x BN): direct, float4
    {
      constexpr int F4 = BN / 4;               // float4s per row
      for (int l = t; l < BK * F4; l += 256) {
        int r = l / F4, c4 = l % F4;
        float4 v = *(const float4*)&B[(size_t)(k0 + r) * BN + c4 * 4];
        *(float4*)&Bs[r][c4 * 4] = v;
      }
    }
    __syncthreads();
#pragma unroll
    for (int kk = 0; kk < BK; ++kk) {
      float4 av = *(const float4*)&As[kk][ty * 4];
      float a[4] = {av.x, av.y, av.z, av.w};
      float b[TN];
#pragma unroll
      for (int j4 = 0; j4 < TN; j4 += 4) {
        float4 bv = *(const float4*)&Bs[kk][tx * TN + j4];
        b[j4 + 0] = bv.x; b[j4 + 1] = bv.y; b[j4 + 2] = bv.z; b[j4 + 3] = bv.w;
      }
#pragma unroll
      for (int i = 0; i < 4; ++i)
#pragma unroll
        for (int j = 0; j < TN; ++j) acc[i][j] += a[i] * b[j];
    }
    __syncthreads();
  }

#pragma unroll
  for (int i = 0; i < 4; ++i) {
    int r = row0 + ty * 4 + i;
    if (r < M) {
#pragma unroll
      for (int j4 = 0; j4 < TN; j4 += 4) {
        int c = tx * TN + j4;
        float4 v = make_float4(acc[i][j4], acc[i][j4 + 1], acc[i][j4 + 2], acc[i][j4 + 3]);
        if (bias) { v.x += bias[c]; v.y += bias[c + 1]; v.z += bias[c + 2]; v.w += bias[c + 3]; }
        *(float4*)&C[(size_t)r * BN + c] = v;
      }
    }
  }
}

// ------------------- aggregation, unrolled x4 -------------------
// one wave per node; lane handles 2 features (float2). D=128 fixed.
__global__ __launch_bounds__(256) void k_agg(const float* __restrict__ t,
                      const int* __restrict__ row_off,
                      const int* __restrict__ csr_src, const float* __restrict__ csr_norm,
                      const float* __restrict__ dinv, const float* __restrict__ bias,
                      float* __restrict__ out, int n) {
  int wave = threadIdx.x >> 6;
  int lane = threadIdx.x & 63;
  int node = blockIdx.x * 4 + wave;
  if (node >= n) return;
  const float2* tp = (const float2*)t;
  float di = dinv[node];
  float self = di * di;
  float2 v = tp[(size_t)node * 64 + lane];
  float ax = self * v.x, ay = self * v.y;
  float bx = 0.f, by = 0.f, cx = 0.f, cy = 0.f, dx = 0.f, dy = 0.f;
  int e0 = row_off[node], e1 = row_off[node + 1];
  int e = e0;
  for (; e + 4 <= e1; e += 4) {
    int s0 = csr_src[e], s1 = csr_src[e + 1], s2 = csr_src[e + 2], s3 = csr_src[e + 3];
    float w0 = csr_norm[e], w1 = csr_norm[e + 1], w2 = csr_norm[e + 2], w3 = csr_norm[e + 3];
    float2 u0 = tp[(size_t)s0 * 64 + lane];
    float2 u1 = tp[(size_t)s1 * 64 + lane];
    float2 u2 = tp[(size_t)s2 * 64 + lane];
    float2 u3 = tp[(size_t)s3 * 64 + lane];
    ax += w0 * u0.x; ay += w0 * u0.y;
    bx += w1 * u1.x; by += w1 * u1.y;
    cx += w2 * u2.x; cy += w2 * u2.y;
    dx += w3 * u3.x; dy += w3 * u3.y;
  }
  for (; e < e1; ++e) {
    int s = csr_src[e];
    float w = csr_norm[e];
    float2 u = tp[(size_t)s * 64 + lane];
    ax += w * u.x; ay += w * u.y;
  }
  float sx = (ax + bx) + (cx + dx);
  float sy = (ay + by) + (cy + dy);
  float2 bb = ((const float2*)bias)[lane];
  sx = fmaxf(sx + bb.x, 0.f);
  sy = fmaxf(sy + bb.y, 0.f);
  ((float2*)(out + (size_t)node * 128))[lane] = make_float2(sx, sy);
}

extern "C" void kernel_launch(void* const* d_in, const int* in_sizes, int n_in,
                              void* d_out, int out_size, void* d_ws, size_t ws_size,
                              hipStream_t stream) {
  const float* x  = (const float*)d_in[0];
  const int*   ei = (const int*)d_in[1];
  const float* W1 = (const float*)d_in[2];
  const float* b1 = (const float*)d_in[3];
  const float* W2 = (const float*)d_in[4];
  const float* b2 = (const float*)d_in[5];
  const float* Wl = (const float*)d_in[6];
  const float* bl = (const float*)d_in[7];
  float* out = (float*)d_out;

  const int D = 128;
  int N = in_sizes[0] / D;
  int E = in_sizes[1] / 2;
  const int* src = ei;
  const int* dst = ei + E;

  // workspace layout
  char* ws = (char*)d_ws;
  float* t_buf = (float*)ws;  ws += (size_t)N * D * sizeof(float);
  float* g_buf = (float*)ws;  ws += (size_t)N * D * sizeof(float);
  int* cnt     = (int*)ws;    ws += (size_t)N * sizeof(int);
  int* row_off = (int*)ws;    ws += ((size_t)N + 1) * sizeof(int);
  int* cursor  = (int*)ws;    ws += (size_t)N * sizeof(int);
  float* dinv  = (float*)ws;  ws += (size_t)N * sizeof(float);
  int* partial = (int*)ws;    ws += 256 * sizeof(int);
  int* csr_src = (int*)ws;    ws += (size_t)E * sizeof(int);
  float* csr_norm = (float*)ws;

  int nb_n = (N + 255) / 256;   // 196 for N=50000 (fits single-block scan2)
  int nb_e = (E + 255) / 256;

  // ---- graph preprocessing ----
  k_zero_i32<<<nb_n, 256, 0, stream>>>(cnt, N);
  k_count<<<nb_e, 256, 0, stream>>>(dst, E, cnt);
  k_scan1<<<nb_n, 256, 0, stream>>>(cnt, N, partial);
  k_scan2<<<1, 256, 0, stream>>>(partial, nb_n);
  k_scan3<<<nb_n, 256, 0, stream>>>(cnt, partial, N, row_off, cursor, dinv);
  k_place<<<nb_e, 256, 0, stream>>>(src, dst, E, cursor, dinv, csr_src, csr_norm);

  int gemm_blocks = (N + 63) / 64;
  int agg_blocks = (N + 3) / 4;

  // ---- layer 1 ----
  gemm_v2<128, 8><<<gemm_blocks, 256, 0, stream>>>(x, W1, nullptr, t_buf, N);
  k_agg<<<agg_blocks, 256, 0, stream>>>(t_buf, row_off, csr_src, csr_norm, dinv, b1, g_buf, N);
  // ---- layer 2 ----
  gemm_v2<128, 8><<<gemm_blocks, 256, 0, stream>>>(g_buf, W2, nullptr, t_buf, N);
  k_agg<<<agg_blocks, 256, 0, stream>>>(t_buf, row_off, csr_src, csr_norm, dinv, b2, g_buf, N);
  // ---- classifier ----
  gemm_v2<64, 4><<<gemm_blocks, 256, 0, stream>>>(g_buf, Wl, bl, out, N);
}

// Round 3
// 323.287 us; speedup vs baseline: 1.3718x; 1.0615x over previous
//
#include <hip/hip_runtime.h>

// -------------------------------------------------------------------------
// GCN: h1 = relu(Agg(x@W1)+b1); h2 = relu(Agg(h1@W2)+b2); out = h2@Wl+bl
// Agg(t)[i] = dinv[i]^2 * t[i] + sum_{e: dst=i} dinv[src]*dinv[i] * t[src]
// R3: GEMMs via bf16x3-split MFMA (hi/lo emulated fp32, no LDS, no barriers);
//     CSR edge entries packed to 8B (one cache-line touch per edge scatter).
// -------------------------------------------------------------------------

typedef __attribute__((ext_vector_type(8))) __bf16 bf16x8;
typedef __attribute__((ext_vector_type(4))) float f32x4;

__global__ void k_zero_i32(int* __restrict__ p, int n) {
  int i = blockIdx.x * blockDim.x + threadIdx.x;
  if (i < n) p[i] = 0;
}

__global__ void k_count(const int* __restrict__ dst, int E, int* __restrict__ cnt) {
  int i = blockIdx.x * blockDim.x + threadIdx.x;
  if (i < E) atomicAdd(&cnt[dst[i]], 1);
}

__global__ void k_scan1(const int* __restrict__ cnt, int n, int* __restrict__ partial) {
  __shared__ int s[256];
  int i = blockIdx.x * 256 + threadIdx.x;
  s[threadIdx.x] = (i < n) ? cnt[i] : 0;
  __syncthreads();
  for (int off = 128; off > 0; off >>= 1) {
    if (threadIdx.x < off) s[threadIdx.x] += s[threadIdx.x + off];
    __syncthreads();
  }
  if (threadIdx.x == 0) partial[blockIdx.x] = s[0];
}

__global__ void k_scan2(int* __restrict__ partial, int nb) {
  __shared__ int s[256];
  int t = threadIdx.x;
  int v = (t < nb) ? partial[t] : 0;
  s[t] = v;
  __syncthreads();
  for (int off = 1; off < 256; off <<= 1) {
    int u = (t >= off) ? s[t - off] : 0;
    __syncthreads();
    s[t] += u;
    __syncthreads();
  }
  if (t < nb) partial[t] = s[t] - v;  // exclusive
}

__global__ void k_scan3(const int* __restrict__ cnt, const int* __restrict__ partial,
                        int n, int* __restrict__ row_off, int* __restrict__ cursor,
                        float* __restrict__ dinv) {
  __shared__ int s[256];
  int t = threadIdx.x;
  int i = blockIdx.x * 256 + t;
  int v = (i < n) ? cnt[i] : 0;
  s[t] = v;
  __syncthreads();
  for (int off = 1; off < 256; off <<= 1) {
    int u = (t >= off) ? s[t - off] : 0;
    __syncthreads();
    s[t] += u;
    __syncthreads();
  }
  int incl = s[t];
  int excl = incl - v;
  int base = partial[blockIdx.x];
  if (i < n) {
    row_off[i] = base + excl;
    cursor[i] = base + excl;
    dinv[i] = rsqrtf((float)(v + 1));
    if (i == n - 1) row_off[n] = base + incl;
  }
}

// packed edge: .x = src node, .y = bit-cast norm weight  (single 8B scatter)
__global__ void k_place(const int* __restrict__ src, const int* __restrict__ dst, int E,
                        int* __restrict__ cursor, const float* __restrict__ dinv,
                        int2* __restrict__ edges) {
  int e = blockIdx.x * blockDim.x + threadIdx.x;
  if (e < E) {
    int s = src[e], d = dst[e];
    int pos = atomicAdd(&cursor[d], 1);
    edges[pos] = make_int2(s, __float_as_int(dinv[s] * dinv[d]));
  }
}

// ------------------- B prep: transpose + hi/lo bf16 split -------------------
// W: [128][N] row-major (K rows, N cols) -> bt_hi/bt_lo: [n][k] K-contiguous
__global__ void k_prepB(const float* __restrict__ W, int N,
                        short* __restrict__ bt_hi, short* __restrict__ bt_lo) {
  int idx = blockIdx.x * 256 + threadIdx.x;
  if (idx >= 128 * N) return;
  int n = idx >> 7, k = idx & 127;
  float v = W[(size_t)k * N + n];
  __bf16 h = (__bf16)v;
  float hf = (float)h;
  __bf16 l = (__bf16)(v - hf);
  bt_hi[idx] = __builtin_bit_cast(short, h);
  bt_lo[idx] = __builtin_bit_cast(short, l);
}

// ------------------- MFMA GEMM (fp32 via bf16 hi/lo split) -------------------
// C[M x N] = A[M x 128] @ B[128 x N] (+bias), N = NT*16 (NT=8 or 4).
// Block = 256 thr = 4 waves; each wave owns 32 rows (2 m-tiles of 16).
// A fp32 loaded straight from global per-lane and split to hi/lo in regs.
// B fragments from pre-split K-contiguous bt arrays (L2-resident).
// 16x16x32 bf16 MFMA. A-frag: A[m=lane&15][k=(lane>>4)*8+j].
// B-frag: B[k=(lane>>4)*8+j][n=lane&15]. C/D: col=lane&15, row=(lane>>4)*4+r.
template <int NT, bool BIAS>
__global__ __launch_bounds__(256) void gemm_mfma(
    const float* __restrict__ A, const short* __restrict__ Bt_hi,
    const short* __restrict__ Bt_lo, const float* __restrict__ bias,
    float* __restrict__ C, int M) {
  constexpr int K = 128;
  constexpr int N = NT * 16;
  int wave = threadIdx.x >> 6;
  int lane = threadIdx.x & 63;
  int lm = lane & 15;   // row within m-tile (A), col within n-tile (B, C)
  int lk = lane >> 4;   // k quad
  int m_base = blockIdx.x * 128 + wave * 32;

  f32x4 acc[2][NT] = {};

  for (int ks = 0; ks < 4; ++ks) {
    int k0 = ks * 32 + lk * 8;
    // B fragments (same for every block -> L2 hits)
    bf16x8 bh[NT], blo[NT];
#pragma unroll
    for (int nt = 0; nt < NT; ++nt) {
      size_t boff = (size_t)(nt * 16 + lm) * K + k0;
      bh[nt] = *(const bf16x8*)&Bt_hi[boff];
      blo[nt] = *(const bf16x8*)&Bt_lo[boff];
    }
#pragma unroll
    for (int mt = 0; mt < 2; ++mt) {
      int row = m_base + mt * 16 + lm;
      float a[8];
      if (row < M) {
        float4 v0 = *(const float4*)&A[(size_t)row * K + k0];
        float4 v1 = *(const float4*)&A[(size_t)row * K + k0 + 4];
        a[0] = v0.x; a[1] = v0.y; a[2] = v0.z; a[3] = v0.w;
        a[4] = v1.x; a[5] = v1.y; a[6] = v1.z; a[7] = v1.w;
      } else {
#pragma unroll
        for (int j = 0; j < 8; ++j) a[j] = 0.f;
      }
      bf16x8 ah, al;
#pragma unroll
      for (int j = 0; j < 8; ++j) {
        __bf16 h = (__bf16)a[j];
        ah[j] = h;
        al[j] = (__bf16)(a[j] - (float)h);
      }
#pragma unroll
      for (int nt = 0; nt < NT; ++nt) {
        acc[mt][nt] = __builtin_amdgcn_mfma_f32_16x16x32_bf16(ah, bh[nt], acc[mt][nt], 0, 0, 0);
        acc[mt][nt] = __builtin_amdgcn_mfma_f32_16x16x32_bf16(ah, blo[nt], acc[mt][nt], 0, 0, 0);
        acc[mt][nt] = __builtin_amdgcn_mfma_f32_16x16x32_bf16(al, bh[nt], acc[mt][nt], 0, 0, 0);
      }
    }
  }

  // epilogue: row = (lane>>4)*4 + r, col = lane&15 within each 16x16 tile
#pragma unroll
  for (int mt = 0; mt < 2; ++mt) {
#pragma unroll
    for (int r = 0; r < 4; ++r) {
      int row = m_base + mt * 16 + lk * 4 + r;
      if (row < M) {
#pragma unroll
        for (int nt = 0; nt < NT; ++nt) {
          int col = nt * 16 + lm;
          float v = acc[mt][nt][r];
          if (BIAS) v += bias[col];
          C[(size_t)row * N + col] = v;
        }
      }
    }
  }
}

// ------------------- aggregation, unrolled x4, packed edges -------------------
__global__ __launch_bounds__(256) void k_agg(const float* __restrict__ t,
                      const int* __restrict__ row_off,
                      const int2* __restrict__ edges,
                      const float* __restrict__ dinv, const float* __restrict__ bias,
                      float* __restrict__ out, int n) {
  int wave = threadIdx.x >> 6;
  int lane = threadIdx.x & 63;
  int node = blockIdx.x * 4 + wave;
  if (node >= n) return;
  const float2* tp = (const float2*)t;
  float di = dinv[node];
  float self = di * di;
  float2 v = tp[(size_t)node * 64 + lane];
  float ax = self * v.x, ay = self * v.y;
  float bx = 0.f, by = 0.f, cx = 0.f, cy = 0.f, dx = 0.f, dy = 0.f;
  int e0 = row_off[node], e1 = row_off[node + 1];
  int e = e0;
  for (; e + 4 <= e1; e += 4) {
    int2 p0 = edges[e], p1 = edges[e + 1], p2 = edges[e + 2], p3 = edges[e + 3];
    float w0 = __int_as_float(p0.y), w1 = __int_as_float(p1.y);
    float w2 = __int_as_float(p2.y), w3 = __int_as_float(p3.y);
    float2 u0 = tp[(size_t)p0.x * 64 + lane];
    float2 u1 = tp[(size_t)p1.x * 64 + lane];
    float2 u2 = tp[(size_t)p2.x * 64 + lane];
    float2 u3 = tp[(size_t)p3.x * 64 + lane];
    ax += w0 * u0.x; ay += w0 * u0.y;
    bx += w1 * u1.x; by += w1 * u1.y;
    cx += w2 * u2.x; cy += w2 * u2.y;
    dx += w3 * u3.x; dy += w3 * u3.y;
  }
  for (; e < e1; ++e) {
    int2 p = edges[e];
    float w = __int_as_float(p.y);
    float2 u = tp[(size_t)p.x * 64 + lane];
    ax += w * u.x; ay += w * u.y;
  }
  float sx = (ax + bx) + (cx + dx);
  float sy = (ay + by) + (cy + dy);
  float2 bb = ((const float2*)bias)[lane];
  sx = fmaxf(sx + bb.x, 0.f);
  sy = fmaxf(sy + bb.y, 0.f);
  ((float2*)(out + (size_t)node * 128))[lane] = make_float2(sx, sy);
}

extern "C" void kernel_launch(void* const* d_in, const int* in_sizes, int n_in,
                              void* d_out, int out_size, void* d_ws, size_t ws_size,
                              hipStream_t stream) {
  const float* x  = (const float*)d_in[0];
  const int*   ei = (const int*)d_in[1];
  const float* W1 = (const float*)d_in[2];
  const float* b1 = (const float*)d_in[3];
  const float* W2 = (const float*)d_in[4];
  const float* b2 = (const float*)d_in[5];
  const float* Wl = (const float*)d_in[6];
  const float* bl = (const float*)d_in[7];
  float* out = (float*)d_out;

  const int D = 128;
  int N = in_sizes[0] / D;
  int E = in_sizes[1] / 2;
  const int* src = ei;
  const int* dst = ei + E;

  // workspace layout (16B-align each chunk)
  uintptr_t ws = (uintptr_t)d_ws;
  auto take = [&](size_t bytes) {
    uintptr_t p = ws;
    ws += (bytes + 15) & ~(size_t)15;
    return p;
  };
  float* t_buf   = (float*)take((size_t)N * D * sizeof(float));
  float* g_buf   = (float*)take((size_t)N * D * sizeof(float));
  int2*  edges   = (int2*)take((size_t)E * 8);
  int*   cnt     = (int*)take((size_t)N * sizeof(int));
  int*   row_off = (int*)take(((size_t)N + 1) * sizeof(int));
  int*   cursor  = (int*)take((size_t)N * sizeof(int));
  float* dinv    = (float*)take((size_t)N * sizeof(float));
  int*   partial = (int*)take(256 * sizeof(int));
  short* bt1_hi  = (short*)take(128 * 128 * 2);
  short* bt1_lo  = (short*)take(128 * 128 * 2);
  short* bt2_hi  = (short*)take(128 * 128 * 2);
  short* bt2_lo  = (short*)take(128 * 128 * 2);
  short* btl_hi  = (short*)take(128 * 64 * 2);
  short* btl_lo  = (short*)take(128 * 64 * 2);

  int nb_n = (N + 255) / 256;   // 196 for N=50000 (fits single-block scan2)
  int nb_e = (E + 255) / 256;

  // ---- graph preprocessing ----
  k_zero_i32<<<nb_n, 256, 0, stream>>>(cnt, N);
  k_count<<<nb_e, 256, 0, stream>>>(dst, E, cnt);
  k_scan1<<<nb_n, 256, 0, stream>>>(cnt, N, partial);
  k_scan2<<<1, 256, 0, stream>>>(partial, nb_n);
  k_scan3<<<nb_n, 256, 0, stream>>>(cnt, partial, N, row_off, cursor, dinv);
  k_place<<<nb_e, 256, 0, stream>>>(src, dst, E, cursor, dinv, edges);

  // ---- weight prep (hi/lo split, transposed) ----
  k_prepB<<<(128 * 128 + 255) / 256, 256, 0, stream>>>(W1, 128, bt1_hi, bt1_lo);
  k_prepB<<<(128 * 128 + 255) / 256, 256, 0, stream>>>(W2, 128, bt2_hi, bt2_lo);
  k_prepB<<<(128 * 64 + 255) / 256, 256, 0, stream>>>(Wl, 64, btl_hi, btl_lo);

  int gemm_blocks = (N + 127) / 128;
  int agg_blocks = (N + 3) / 4;

  // ---- layer 1 ----
  gemm_mfma<8, false><<<gemm_blocks, 256, 0, stream>>>(x, bt1_hi, bt1_lo, nullptr, t_buf, N);
  k_agg<<<agg_blocks, 256, 0, stream>>>(t_buf, row_off, edges, dinv, b1, g_buf, N);
  // ---- layer 2 ----
  gemm_mfma<8, false><<<gemm_blocks, 256, 0, stream>>>(g_buf, bt2_hi, bt2_lo, nullptr, t_buf, N);
  k_agg<<<agg_blocks, 256, 0, stream>>>(t_buf, row_off, edges, dinv, b2, g_buf, N);
  // ---- classifier ----
  gemm_mfma<4, true><<<gemm_blocks, 256, 0, stream>>>(g_buf, btl_hi, btl_lo, bl, out, N);
}

// Round 4
// 268.817 us; speedup vs baseline: 1.6498x; 1.2026x over previous
//
#include <hip/hip_runtime.h>

// -------------------------------------------------------------------------
// GCN: h1 = relu(Agg(x@W1)+b1); h2 = relu(Agg(h1@W2)+b2); out = h2@Wl+bl
// R4: GEMM = bf16x3-split MFMA with B staged in LDS (XOR-swizzled, 64KB,
//     conflict-free ds_read_b128) and A pre-split to bf16 hi/lo (k_prepX /
//     k_agg epilogue). Inter-layer activations carried as bf16 (halves
//     gather traffic in k_agg). CSR edges packed 8B.
// -------------------------------------------------------------------------

typedef __attribute__((ext_vector_type(8))) __bf16 bf16x8;
typedef __attribute__((ext_vector_type(8))) short short8;
typedef __attribute__((ext_vector_type(4))) float f32x4;

__device__ inline float bf_lo(unsigned u) { return __uint_as_float(u << 16); }
__device__ inline float bf_hi(unsigned u) { return __uint_as_float(u & 0xffff0000u); }
__device__ inline unsigned short f2bf(float v) {
  return __builtin_bit_cast(unsigned short, (__bf16)v);
}

__global__ void k_count(const int* __restrict__ dst, int E, int* __restrict__ cnt) {
  int i = blockIdx.x * blockDim.x + threadIdx.x;
  if (i < E) atomicAdd(&cnt[dst[i]], 1);
}

__global__ void k_scan1(const int* __restrict__ cnt, int n, int* __restrict__ partial) {
  __shared__ int s[256];
  int i = blockIdx.x * 256 + threadIdx.x;
  s[threadIdx.x] = (i < n) ? cnt[i] : 0;
  __syncthreads();
  for (int off = 128; off > 0; off >>= 1) {
    if (threadIdx.x < off) s[threadIdx.x] += s[threadIdx.x + off];
    __syncthreads();
  }
  if (threadIdx.x == 0) partial[blockIdx.x] = s[0];
}

__global__ void k_scan2(int* __restrict__ partial, int nb) {
  __shared__ int s[256];
  int t = threadIdx.x;
  int v = (t < nb) ? partial[t] : 0;
  s[t] = v;
  __syncthreads();
  for (int off = 1; off < 256; off <<= 1) {
    int u = (t >= off) ? s[t - off] : 0;
    __syncthreads();
    s[t] += u;
    __syncthreads();
  }
  if (t < nb) partial[t] = s[t] - v;  // exclusive
}

__global__ void k_scan3(const int* __restrict__ cnt, const int* __restrict__ partial,
                        int n, int* __restrict__ row_off, int* __restrict__ cursor,
                        float* __restrict__ dinv) {
  __shared__ int s[256];
  int t = threadIdx.x;
  int i = blockIdx.x * 256 + t;
  int v = (i < n) ? cnt[i] : 0;
  s[t] = v;
  __syncthreads();
  for (int off = 1; off < 256; off <<= 1) {
    int u = (t >= off) ? s[t - off] : 0;
    __syncthreads();
    s[t] += u;
    __syncthreads();
  }
  int incl = s[t];
  int excl = incl - v;
  int base = partial[blockIdx.x];
  if (i < n) {
    row_off[i] = base + excl;
    cursor[i] = base + excl;
    dinv[i] = rsqrtf((float)(v + 1));
    if (i == n - 1) row_off[n] = base + incl;
  }
}

// packed edge: .x = src node, .y = bit-cast norm weight  (single 8B scatter)
__global__ void k_place(const int* __restrict__ src, const int* __restrict__ dst, int E,
                        int* __restrict__ cursor, const float* __restrict__ dinv,
                        int2* __restrict__ edges) {
  int e = blockIdx.x * blockDim.x + threadIdx.x;
  if (e < E) {
    int s = src[e], d = dst[e];
    int pos = atomicAdd(&cursor[d], 1);
    edges[pos] = make_int2(s, __float_as_int(dinv[s] * dinv[d]));
  }
}

// ---- weight prep: transpose + hi/lo bf16 split, all three weights fused ----
// W: [128][N] row-major -> bt[n][k] (K-contiguous)
__global__ void k_prepW(const float* __restrict__ W1, const float* __restrict__ W2,
                        const float* __restrict__ Wl,
                        unsigned short* __restrict__ b1h, unsigned short* __restrict__ b1l,
                        unsigned short* __restrict__ b2h, unsigned short* __restrict__ b2l,
                        unsigned short* __restrict__ blh, unsigned short* __restrict__ bll) {
  int idx = blockIdx.x * 256 + threadIdx.x;
  const float* W;
  unsigned short *bh, *bl_;
  int N, local;
  if (idx < 16384)      { W = W1; bh = b1h; bl_ = b1l; N = 128; local = idx; }
  else if (idx < 32768) { W = W2; bh = b2h; bl_ = b2l; N = 128; local = idx - 16384; }
  else if (idx < 40960) { W = Wl; bh = blh; bl_ = bll; N = 64;  local = idx - 32768; }
  else return;
  int n = local >> 7, k = local & 127;
  float v = W[(size_t)k * N + n];
  __bf16 h = (__bf16)v;
  bh[local] = __builtin_bit_cast(unsigned short, h);
  bl_[local] = f2bf(v - (float)h);
}

// ---- x prep: fp32 -> bf16 hi/lo ----
__global__ __launch_bounds__(256) void k_prepX(const float* __restrict__ x,
                                               unsigned short* __restrict__ xh,
                                               unsigned short* __restrict__ xl, int total4) {
  int i = blockIdx.x * 256 + threadIdx.x;
  if (i >= total4) return;
  float4 v = ((const float4*)x)[i];
  ushort4 h, l;
  __bf16 h0 = (__bf16)v.x; h.x = __builtin_bit_cast(unsigned short, h0); l.x = f2bf(v.x - (float)h0);
  __bf16 h1 = (__bf16)v.y; h.y = __builtin_bit_cast(unsigned short, h1); l.y = f2bf(v.y - (float)h1);
  __bf16 h2 = (__bf16)v.z; h.z = __builtin_bit_cast(unsigned short, h2); l.z = f2bf(v.z - (float)h2);
  __bf16 h3 = (__bf16)v.w; h.w = __builtin_bit_cast(unsigned short, h3); l.w = f2bf(v.w - (float)h3);
  ((ushort4*)xh)[i] = h;
  ((ushort4*)xl)[i] = l;
}

// ------------------- MFMA GEMM, B in LDS -------------------
// C[M x N] = A[M x 128] @ B[128 x N] (+bias), N = NT*16.
// A pre-split bf16 hi/lo; B pre-split + transposed [n][k].
// Block = 256 thr = 4 waves; wave owns 32 rows (2 m-tiles).
// B staged in LDS with XOR-swizzled 16B chunks (bank-conflict-free b128).
// 3-term split: hi*hi + hi*lo + lo*hi  (~2^-17 rel error).
template <int NT, bool BIAS, bool OUT_BF16>
__global__ __launch_bounds__(256) void gemm2(
    const unsigned short* __restrict__ Ahi, const unsigned short* __restrict__ Alo,
    const unsigned short* __restrict__ Bhi, const unsigned short* __restrict__ Blo,
    const float* __restrict__ bias, void* __restrict__ Cout, int M) {
  constexpr int K = 128;
  constexpr int NCOL = NT * 16;
  __shared__ alignas(16) unsigned short lbh[NCOL * K];
  __shared__ alignas(16) unsigned short lbl[NCOL * K];
  int t = threadIdx.x;
  // cooperative swizzled stage: chunk q of row r stored at chunk (q ^ (r&15))
  for (int c = t; c < NCOL * 16; c += 256) {
    int r = c >> 4, q = c & 15;
    int sq = q ^ (r & 15);
    *(short8*)&lbh[r * K + sq * 8] = *(const short8*)&Bhi[r * K + q * 8];
    *(short8*)&lbl[r * K + sq * 8] = *(const short8*)&Blo[r * K + q * 8];
  }
  __syncthreads();

  int lane = t & 63, wave = t >> 6;
  int lm = lane & 15, lk = lane >> 4;
  int m_base = blockIdx.x * 128 + wave * 32;

  f32x4 acc[2][NT] = {};
  const short8 zero8 = {0, 0, 0, 0, 0, 0, 0, 0};

#pragma unroll
  for (int ks = 0; ks < 4; ++ks) {
    int k0 = ks * 32 + lk * 8;           // shorts
    int chunk = (ks * 4 + lk);           // 16B-chunk index within row
    bf16x8 bh[NT], bl[NT];
#pragma unroll
    for (int nt = 0; nt < NT; ++nt) {
      int r = nt * 16 + lm;
      int sq = chunk ^ lm;               // matches store swizzle (r&15 == lm)
      bh[nt] = *(const bf16x8*)&lbh[r * K + sq * 8];
      bl[nt] = *(const bf16x8*)&lbl[r * K + sq * 8];
    }
#pragma unroll
    for (int mt = 0; mt < 2; ++mt) {
      int row = m_base + mt * 16 + lm;
      bf16x8 ah, al;
      if (row < M) {
        ah = *(const bf16x8*)&Ahi[(size_t)row * K + k0];
        al = *(const bf16x8*)&Alo[(size_t)row * K + k0];
      } else {
        ah = __builtin_bit_cast(bf16x8, zero8);
        al = __builtin_bit_cast(bf16x8, zero8);
      }
#pragma unroll
      for (int nt = 0; nt < NT; ++nt) {
        acc[mt][nt] = __builtin_amdgcn_mfma_f32_16x16x32_bf16(ah, bh[nt], acc[mt][nt], 0, 0, 0);
        acc[mt][nt] = __builtin_amdgcn_mfma_f32_16x16x32_bf16(ah, bl[nt], acc[mt][nt], 0, 0, 0);
        acc[mt][nt] = __builtin_amdgcn_mfma_f32_16x16x32_bf16(al, bh[nt], acc[mt][nt], 0, 0, 0);
      }
    }
  }

  // epilogue: row = (lane>>4)*4 + r, col = lane&15 within each 16x16 tile
#pragma unroll
  for (int mt = 0; mt < 2; ++mt) {
#pragma unroll
    for (int r = 0; r < 4; ++r) {
      int row = m_base + mt * 16 + lk * 4 + r;
      if (row < M) {
#pragma unroll
        for (int nt = 0; nt < NT; ++nt) {
          int col = nt * 16 + lm;
          float v = acc[mt][nt][r];
          if (BIAS) v += bias[col];
          if (OUT_BF16)
            ((unsigned short*)Cout)[(size_t)row * NCOL + col] = f2bf(v);
          else
            ((float*)Cout)[(size_t)row * NCOL + col] = v;
        }
      }
    }
  }
}

// ------------------- aggregation: bf16 gather, hi/lo bf16 output -------------------
// one wave per node; lane handles 2 features (4B load). D=128 fixed.
__global__ __launch_bounds__(256) void k_agg(const unsigned short* __restrict__ t,
                      const int* __restrict__ row_off,
                      const int2* __restrict__ edges,
                      const float* __restrict__ dinv, const float* __restrict__ bias,
                      unsigned short* __restrict__ ghi, unsigned short* __restrict__ glo,
                      int n) {
  int wave = threadIdx.x >> 6;
  int lane = threadIdx.x & 63;
  int node = blockIdx.x * 4 + wave;
  if (node >= n) return;
  float di = dinv[node];
  float self = di * di;
  unsigned sv = *(const unsigned*)&t[(size_t)node * 128 + lane * 2];
  float ax = self * bf_lo(sv), ay = self * bf_hi(sv);
  float bx = 0.f, by = 0.f, cx = 0.f, cy = 0.f, dx = 0.f, dy = 0.f;
  int e0 = row_off[node], e1 = row_off[node + 1];
  int e = e0;
  for (; e + 4 <= e1; e += 4) {
    int2 p0 = edges[e], p1 = edges[e + 1], p2 = edges[e + 2], p3 = edges[e + 3];
    float w0 = __int_as_float(p0.y), w1 = __int_as_float(p1.y);
    float w2 = __int_as_float(p2.y), w3 = __int_as_float(p3.y);
    unsigned u0 = *(const unsigned*)&t[(size_t)p0.x * 128 + lane * 2];
    unsigned u1 = *(const unsigned*)&t[(size_t)p1.x * 128 + lane * 2];
    unsigned u2 = *(const unsigned*)&t[(size_t)p2.x * 128 + lane * 2];
    unsigned u3 = *(const unsigned*)&t[(size_t)p3.x * 128 + lane * 2];
    ax += w0 * bf_lo(u0); ay += w0 * bf_hi(u0);
    bx += w1 * bf_lo(u1); by += w1 * bf_hi(u1);
    cx += w2 * bf_lo(u2); cy += w2 * bf_hi(u2);
    dx += w3 * bf_lo(u3); dy += w3 * bf_hi(u3);
  }
  for (; e < e1; ++e) {
    int2 p = edges[e];
    float w = __int_as_float(p.y);
    unsigned u = *(const unsigned*)&t[(size_t)p.x * 128 + lane * 2];
    ax += w * bf_lo(u); ay += w * bf_hi(u);
  }
  float sx = (ax + bx) + (cx + dx);
  float sy = (ay + by) + (cy + dy);
  float2 bb = ((const float2*)bias)[lane];
  sx = fmaxf(sx + bb.x, 0.f);
  sy = fmaxf(sy + bb.y, 0.f);
  // hi/lo split for next GEMM's A operand
  __bf16 hx = (__bf16)sx; float hxf = (float)hx;
  __bf16 hy = (__bf16)sy; float hyf = (float)hy;
  ushort2 ho, lo;
  ho.x = __builtin_bit_cast(unsigned short, hx);
  ho.y = __builtin_bit_cast(unsigned short, hy);
  lo.x = f2bf(sx - hxf);
  lo.y = f2bf(sy - hyf);
  *(ushort2*)&ghi[(size_t)node * 128 + lane * 2] = ho;
  *(ushort2*)&glo[(size_t)node * 128 + lane * 2] = lo;
}

extern "C" void kernel_launch(void* const* d_in, const int* in_sizes, int n_in,
                              void* d_out, int out_size, void* d_ws, size_t ws_size,
                              hipStream_t stream) {
  const float* x  = (const float*)d_in[0];
  const int*   ei = (const int*)d_in[1];
  const float* W1 = (const float*)d_in[2];
  const float* b1 = (const float*)d_in[3];
  const float* W2 = (const float*)d_in[4];
  const float* b2 = (const float*)d_in[5];
  const float* Wl = (const float*)d_in[6];
  const float* bl = (const float*)d_in[7];
  float* out = (float*)d_out;

  const int D = 128;
  int N = in_sizes[0] / D;
  int E = in_sizes[1] / 2;
  const int* src = ei;
  const int* dst = ei + E;

  // workspace layout (16B-align each chunk)
  uintptr_t ws = (uintptr_t)d_ws;
  auto take = [&](size_t bytes) {
    uintptr_t p = ws;
    ws += (bytes + 15) & ~(size_t)15;
    return p;
  };
  unsigned short* t_bf = (unsigned short*)take((size_t)N * D * 2);  // bf16 GEMM out
  unsigned short* xh   = (unsigned short*)take((size_t)N * D * 2);  // also g_hi
  unsigned short* xl   = (unsigned short*)take((size_t)N * D * 2);  // also g_lo
  int2*  edges   = (int2*)take((size_t)E * 8);
  int*   cnt     = (int*)take((size_t)N * sizeof(int));
  int*   row_off = (int*)take(((size_t)N + 1) * sizeof(int));
  int*   cursor  = (int*)take((size_t)N * sizeof(int));
  float* dinv    = (float*)take((size_t)N * sizeof(float));
  int*   partial = (int*)take(256 * sizeof(int));
  unsigned short* b1h = (unsigned short*)take(128 * 128 * 2);
  unsigned short* b1l = (unsigned short*)take(128 * 128 * 2);
  unsigned short* b2h = (unsigned short*)take(128 * 128 * 2);
  unsigned short* b2l = (unsigned short*)take(128 * 128 * 2);
  unsigned short* blh = (unsigned short*)take(128 * 64 * 2);
  unsigned short* bll = (unsigned short*)take(128 * 64 * 2);

  int nb_n = (N + 255) / 256;   // 196 for N=50000 (fits single-block scan2)
  int nb_e = (E + 255) / 256;

  // ---- graph preprocessing ----
  hipMemsetAsync(cnt, 0, (size_t)N * sizeof(int), stream);
  k_count<<<nb_e, 256, 0, stream>>>(dst, E, cnt);
  k_scan1<<<nb_n, 256, 0, stream>>>(cnt, N, partial);
  k_scan2<<<1, 256, 0, stream>>>(partial, nb_n);
  k_scan3<<<nb_n, 256, 0, stream>>>(cnt, partial, N, row_off, cursor, dinv);
  k_place<<<nb_e, 256, 0, stream>>>(src, dst, E, cursor, dinv, edges);

  // ---- operand prep ----
  k_prepW<<<(40960 + 255) / 256, 256, 0, stream>>>(W1, W2, Wl, b1h, b1l, b2h, b2l, blh, bll);
  int total4 = N * D / 4;
  k_prepX<<<(total4 + 255) / 256, 256, 0, stream>>>(x, xh, xl, total4);

  int gemm_blocks = (N + 127) / 128;
  int agg_blocks = (N + 3) / 4;

  // ---- layer 1 ----
  gemm2<8, false, true><<<gemm_blocks, 256, 0, stream>>>(xh, xl, b1h, b1l, nullptr, t_bf, N);
  k_agg<<<agg_blocks, 256, 0, stream>>>(t_bf, row_off, edges, dinv, b1, xh, xl, N);
  // ---- layer 2 ----
  gemm2<8, false, true><<<gemm_blocks, 256, 0, stream>>>(xh, xl, b2h, b2l, nullptr, t_bf, N);
  k_agg<<<agg_blocks, 256, 0, stream>>>(t_bf, row_off, edges, dinv, b2, xh, xl, N);
  // ---- classifier ----
  gemm2<4, true, false><<<gemm_blocks, 256, 0, stream>>>(xh, xl, blh, bll, bl, out, N);
}

// Round 5
// 260.638 us; speedup vs baseline: 1.7015x; 1.0314x over previous
//
#include <hip/hip_runtime.h>

// -------------------------------------------------------------------------
// GCN: h1 = relu(Agg(x@W1)+b1); h2 = relu(Agg(h1@W2)+b2); out = h2@Wl+bl
// R5: k_agg half-wave dual-edge (8 outstanding gathers, fewer VALU/edge);
//     k_place nontemporal stores; GEMM1 splits fp32 A in-register (prepX
//     removed); scan2 folded into scan3 (masked partial reduce).
// -------------------------------------------------------------------------

typedef __attribute__((ext_vector_type(8))) __bf16 bf16x8;
typedef __attribute__((ext_vector_type(8))) short short8;
typedef __attribute__((ext_vector_type(4))) float f32x4;

__device__ inline float bf_lo(unsigned u) { return __uint_as_float(u << 16); }
__device__ inline float bf_hi(unsigned u) { return __uint_as_float(u & 0xffff0000u); }
__device__ inline unsigned short f2bf(float v) {
  return __builtin_bit_cast(unsigned short, (__bf16)v);
}

__global__ void k_count(const int* __restrict__ dst, int E, int* __restrict__ cnt) {
  int i = blockIdx.x * blockDim.x + threadIdx.x;
  if (i < E) atomicAdd(&cnt[dst[i]], 1);
}

__global__ void k_scan1(const int* __restrict__ cnt, int n, int* __restrict__ partial) {
  __shared__ int s[256];
  int i = blockIdx.x * 256 + threadIdx.x;
  s[threadIdx.x] = (i < n) ? cnt[i] : 0;
  __syncthreads();
  for (int off = 128; off > 0; off >>= 1) {
    if (threadIdx.x < off) s[threadIdx.x] += s[threadIdx.x + off];
    __syncthreads();
  }
  if (threadIdx.x == 0) partial[blockIdx.x] = s[0];
}

// scan3 with built-in base reduction (no separate scan2 pass)
__global__ void k_scan3(const int* __restrict__ cnt, const int* __restrict__ partial,
                        int nb, int n, int* __restrict__ row_off, int* __restrict__ cursor,
                        float* __restrict__ dinv) {
  __shared__ int s[256];
  __shared__ int base_s;
  int t = threadIdx.x;
  // base = sum of partial[0..blockIdx.x-1]
  s[t] = (t < nb && t < (int)blockIdx.x) ? partial[t] : 0;
  __syncthreads();
  for (int off = 128; off > 0; off >>= 1) {
    if (t < off) s[t] += s[t + off];
    __syncthreads();
  }
  if (t == 0) base_s = s[0];
  __syncthreads();
  int base = base_s;
  __syncthreads();

  int i = blockIdx.x * 256 + t;
  int v = (i < n) ? cnt[i] : 0;
  s[t] = v;
  __syncthreads();
  for (int off = 1; off < 256; off <<= 1) {
    int u = (t >= off) ? s[t - off] : 0;
    __syncthreads();
    s[t] += u;
    __syncthreads();
  }
  int incl = s[t];
  int excl = incl - v;
  if (i < n) {
    row_off[i] = base + excl;
    cursor[i] = base + excl;
    dinv[i] = rsqrtf((float)(v + 1));
    if (i == n - 1) row_off[n] = base + incl;
  }
}

// packed edge: low32 = src node, high32 = bit-cast norm weight; NT 8B scatter
__global__ void k_place(const int* __restrict__ src, const int* __restrict__ dst, int E,
                        int* __restrict__ cursor, const float* __restrict__ dinv,
                        unsigned long long* __restrict__ edges) {
  int e = blockIdx.x * blockDim.x + threadIdx.x;
  if (e < E) {
    int s = src[e], d = dst[e];
    int pos = atomicAdd(&cursor[d], 1);
    unsigned long long packed =
        (unsigned long long)(unsigned)s |
        ((unsigned long long)__float_as_uint(dinv[s] * dinv[d]) << 32);
    __builtin_nontemporal_store(packed, &edges[pos]);
  }
}

// ---- weight prep: transpose + hi/lo bf16 split, all three weights fused ----
__global__ void k_prepW(const float* __restrict__ W1, const float* __restrict__ W2,
                        const float* __restrict__ Wl,
                        unsigned short* __restrict__ b1h, unsigned short* __restrict__ b1l,
                        unsigned short* __restrict__ b2h, unsigned short* __restrict__ b2l,
                        unsigned short* __restrict__ blh, unsigned short* __restrict__ bll) {
  int idx = blockIdx.x * 256 + threadIdx.x;
  const float* W;
  unsigned short *bh, *bl_;
  int N, local;
  if (idx < 16384)      { W = W1; bh = b1h; bl_ = b1l; N = 128; local = idx; }
  else if (idx < 32768) { W = W2; bh = b2h; bl_ = b2l; N = 128; local = idx - 16384; }
  else if (idx < 40960) { W = Wl; bh = blh; bl_ = bll; N = 64;  local = idx - 32768; }
  else return;
  int n = local >> 7, k = local & 127;
  float v = W[(size_t)k * N + n];
  __bf16 h = (__bf16)v;
  bh[local] = __builtin_bit_cast(unsigned short, h);
  bl_[local] = f2bf(v - (float)h);
}

// ------------------- MFMA GEMM, B in LDS -------------------
// C[M x N] = A[M x 128] @ B[128 x N] (+bias), N = NT*16.
// A either fp32 (split in-register) or pre-split bf16 hi/lo.
// B pre-split + transposed [n][k], staged in LDS XOR-swizzled.
// 3-term split: hi*hi + hi*lo + lo*hi  (~2^-17 rel error).
template <int NT, bool A32, bool BIAS, bool OUT_BF16>
__global__ __launch_bounds__(256) void gemm2(
    const void* __restrict__ Ahi_, const unsigned short* __restrict__ Alo,
    const unsigned short* __restrict__ Bhi, const unsigned short* __restrict__ Blo,
    const float* __restrict__ bias, void* __restrict__ Cout, int M) {
  constexpr int K = 128;
  constexpr int NCOL = NT * 16;
  __shared__ alignas(16) unsigned short lbh[NCOL * K];
  __shared__ alignas(16) unsigned short lbl[NCOL * K];
  int t = threadIdx.x;
  for (int c = t; c < NCOL * 16; c += 256) {
    int r = c >> 4, q = c & 15;
    int sq = q ^ (r & 15);
    *(short8*)&lbh[r * K + sq * 8] = *(const short8*)&Bhi[r * K + q * 8];
    *(short8*)&lbl[r * K + sq * 8] = *(const short8*)&Blo[r * K + q * 8];
  }
  __syncthreads();

  int lane = t & 63, wave = t >> 6;
  int lm = lane & 15, lk = lane >> 4;
  int m_base = blockIdx.x * 128 + wave * 32;

  f32x4 acc[2][NT] = {};
  const short8 zero8 = {0, 0, 0, 0, 0, 0, 0, 0};

#pragma unroll
  for (int ks = 0; ks < 4; ++ks) {
    int k0 = ks * 32 + lk * 8;           // element index
    int chunk = (ks * 4 + lk);           // 16B-chunk index within row
    bf16x8 bh[NT], bl[NT];
#pragma unroll
    for (int nt = 0; nt < NT; ++nt) {
      int r = nt * 16 + lm;
      int sq = chunk ^ lm;
      bh[nt] = *(const bf16x8*)&lbh[r * K + sq * 8];
      bl[nt] = *(const bf16x8*)&lbl[r * K + sq * 8];
    }
#pragma unroll
    for (int mt = 0; mt < 2; ++mt) {
      int row = m_base + mt * 16 + lm;
      bf16x8 ah, al;
      if (A32) {
        const float* Af = (const float*)Ahi_;
        if (row < M) {
          float4 v0 = *(const float4*)&Af[(size_t)row * K + k0];
          float4 v1 = *(const float4*)&Af[(size_t)row * K + k0 + 4];
          float a[8] = {v0.x, v0.y, v0.z, v0.w, v1.x, v1.y, v1.z, v1.w};
#pragma unroll
          for (int j = 0; j < 8; ++j) {
            __bf16 h = (__bf16)a[j];
            ah[j] = h;
            al[j] = (__bf16)(a[j] - (float)h);
          }
        } else {
          ah = __builtin_bit_cast(bf16x8, zero8);
          al = __builtin_bit_cast(bf16x8, zero8);
        }
      } else {
        const unsigned short* Ahi = (const unsigned short*)Ahi_;
        if (row < M) {
          ah = *(const bf16x8*)&Ahi[(size_t)row * K + k0];
          al = *(const bf16x8*)&Alo[(size_t)row * K + k0];
        } else {
          ah = __builtin_bit_cast(bf16x8, zero8);
          al = __builtin_bit_cast(bf16x8, zero8);
        }
      }
#pragma unroll
      for (int nt = 0; nt < NT; ++nt) {
        acc[mt][nt] = __builtin_amdgcn_mfma_f32_16x16x32_bf16(ah, bh[nt], acc[mt][nt], 0, 0, 0);
        acc[mt][nt] = __builtin_amdgcn_mfma_f32_16x16x32_bf16(ah, bl[nt], acc[mt][nt], 0, 0, 0);
        acc[mt][nt] = __builtin_amdgcn_mfma_f32_16x16x32_bf16(al, bh[nt], acc[mt][nt], 0, 0, 0);
      }
    }
  }

#pragma unroll
  for (int mt = 0; mt < 2; ++mt) {
#pragma unroll
    for (int r = 0; r < 4; ++r) {
      int row = m_base + mt * 16 + lk * 4 + r;
      if (row < M) {
#pragma unroll
        for (int nt = 0; nt < NT; ++nt) {
          int col = nt * 16 + lm;
          float v = acc[mt][nt][r];
          if (BIAS) v += bias[col];
          if (OUT_BF16)
            ((unsigned short*)Cout)[(size_t)row * NCOL + col] = f2bf(v);
          else
            ((float*)Cout)[(size_t)row * NCOL + col] = v;
        }
      }
    }
  }
}

// ------------------- aggregation: half-wave dual-edge bf16 gather -------------------
// one wave per node; two 32-lane halves each process alternate edges.
// lane covers 4 features (8B bf16). Cross-half reduce via shfl_xor(32).
__global__ __launch_bounds__(256) void k_agg(const unsigned short* __restrict__ t,
                      const int* __restrict__ row_off,
                      const int2* __restrict__ edges,
                      const float* __restrict__ dinv, const float* __restrict__ bias,
                      unsigned short* __restrict__ ghi, unsigned short* __restrict__ glo,
                      int n) {
  int wave = threadIdx.x >> 6;
  int lane = threadIdx.x & 63;
  int half = lane >> 5;
  int hl = lane & 31;           // lane within half: features hl*4 .. hl*4+3
  int node = blockIdx.x * 4 + wave;
  if (node >= n) return;
  int e0 = row_off[node], e1 = row_off[node + 1];

  float4 a0 = {0,0,0,0}, a1 = {0,0,0,0}, a2 = {0,0,0,0}, a3 = {0,0,0,0};
  int e = e0 + half;
  for (; e + 6 < e1; e += 8) {
    int2 p0 = edges[e],     p1 = edges[e + 2];
    int2 p2 = edges[e + 4], p3 = edges[e + 6];
    uint2 u0 = *(const uint2*)&t[(size_t)p0.x * 128 + hl * 4];
    uint2 u1 = *(const uint2*)&t[(size_t)p1.x * 128 + hl * 4];
    uint2 u2 = *(const uint2*)&t[(size_t)p2.x * 128 + hl * 4];
    uint2 u3 = *(const uint2*)&t[(size_t)p3.x * 128 + hl * 4];
    float w0 = __int_as_float(p0.y), w1 = __int_as_float(p1.y);
    float w2 = __int_as_float(p2.y), w3 = __int_as_float(p3.y);
    a0.x += w0 * bf_lo(u0.x); a0.y += w0 * bf_hi(u0.x);
    a0.z += w0 * bf_lo(u0.y); a0.w += w0 * bf_hi(u0.y);
    a1.x += w1 * bf_lo(u1.x); a1.y += w1 * bf_hi(u1.x);
    a1.z += w1 * bf_lo(u1.y); a1.w += w1 * bf_hi(u1.y);
    a2.x += w2 * bf_lo(u2.x); a2.y += w2 * bf_hi(u2.x);
    a2.z += w2 * bf_lo(u2.y); a2.w += w2 * bf_hi(u2.y);
    a3.x += w3 * bf_lo(u3.x); a3.y += w3 * bf_hi(u3.x);
    a3.z += w3 * bf_lo(u3.y); a3.w += w3 * bf_hi(u3.y);
  }
  for (; e < e1; e += 2) {
    int2 p = edges[e];
    uint2 u = *(const uint2*)&t[(size_t)p.x * 128 + hl * 4];
    float w = __int_as_float(p.y);
    a0.x += w * bf_lo(u.x); a0.y += w * bf_hi(u.x);
    a0.z += w * bf_lo(u.y); a0.w += w * bf_hi(u.y);
  }
  float sx = (a0.x + a1.x) + (a2.x + a3.x);
  float sy = (a0.y + a1.y) + (a2.y + a3.y);
  float sz = (a0.z + a1.z) + (a2.z + a3.z);
  float sw = (a0.w + a1.w) + (a2.w + a3.w);
  sx += __shfl_xor(sx, 32);
  sy += __shfl_xor(sy, 32);
  sz += __shfl_xor(sz, 32);
  sw += __shfl_xor(sw, 32);
  if (half == 0) {
    float di = dinv[node];
    float self = di * di;
    uint2 sv = *(const uint2*)&t[(size_t)node * 128 + hl * 4];
    sx += self * bf_lo(sv.x); sy += self * bf_hi(sv.x);
    sz += self * bf_lo(sv.y); sw += self * bf_hi(sv.y);
    float4 bb = *(const float4*)&bias[hl * 4];
    sx = fmaxf(sx + bb.x, 0.f); sy = fmaxf(sy + bb.y, 0.f);
    sz = fmaxf(sz + bb.z, 0.f); sw = fmaxf(sw + bb.w, 0.f);
    __bf16 hx = (__bf16)sx, hy = (__bf16)sy, hz = (__bf16)sz, hw = (__bf16)sw;
    ushort4 ho, lo;
    ho.x = __builtin_bit_cast(unsigned short, hx);
    ho.y = __builtin_bit_cast(unsigned short, hy);
    ho.z = __builtin_bit_cast(unsigned short, hz);
    ho.w = __builtin_bit_cast(unsigned short, hw);
    lo.x = f2bf(sx - (float)hx);
    lo.y = f2bf(sy - (float)hy);
    lo.z = f2bf(sz - (float)hz);
    lo.w = f2bf(sw - (float)hw);
    *(ushort4*)&ghi[(size_t)node * 128 + hl * 4] = ho;
    *(ushort4*)&glo[(size_t)node * 128 + hl * 4] = lo;
  }
}

extern "C" void kernel_launch(void* const* d_in, const int* in_sizes, int n_in,
                              void* d_out, int out_size, void* d_ws, size_t ws_size,
                              hipStream_t stream) {
  const float* x  = (const float*)d_in[0];
  const int*   ei = (const int*)d_in[1];
  const float* W1 = (const float*)d_in[2];
  const float* b1 = (const float*)d_in[3];
  const float* W2 = (const float*)d_in[4];
  const float* b2 = (const float*)d_in[5];
  const float* Wl = (const float*)d_in[6];
  const float* bl = (const float*)d_in[7];
  float* out = (float*)d_out;

  const int D = 128;
  int N = in_sizes[0] / D;
  int E = in_sizes[1] / 2;
  const int* src = ei;
  const int* dst = ei + E;

  uintptr_t ws = (uintptr_t)d_ws;
  auto take = [&](size_t bytes) {
    uintptr_t p = ws;
    ws += (bytes + 15) & ~(size_t)15;
    return p;
  };
  unsigned short* t_bf = (unsigned short*)take((size_t)N * D * 2);  // bf16 GEMM out
  unsigned short* xh   = (unsigned short*)take((size_t)N * D * 2);  // agg out hi
  unsigned short* xl   = (unsigned short*)take((size_t)N * D * 2);  // agg out lo
  unsigned long long* edges = (unsigned long long*)take((size_t)E * 8);
  int*   cnt     = (int*)take((size_t)N * sizeof(int));
  int*   row_off = (int*)take(((size_t)N + 1) * sizeof(int));
  int*   cursor  = (int*)take((size_t)N * sizeof(int));
  float* dinv    = (float*)take((size_t)N * sizeof(float));
  int*   partial = (int*)take(256 * sizeof(int));
  unsigned short* b1h = (unsigned short*)take(128 * 128 * 2);
  unsigned short* b1l = (unsigned short*)take(128 * 128 * 2);
  unsigned short* b2h = (unsigned short*)take(128 * 128 * 2);
  unsigned short* b2l = (unsigned short*)take(128 * 128 * 2);
  unsigned short* blh = (unsigned short*)take(128 * 64 * 2);
  unsigned short* bll = (unsigned short*)take(128 * 64 * 2);

  int nb_n = (N + 255) / 256;   // 196 for N=50000 (single-block base reduce ok)
  int nb_e = (E + 255) / 256;

  // ---- graph preprocessing ----
  hipMemsetAsync(cnt, 0, (size_t)N * sizeof(int), stream);
  k_count<<<nb_e, 256, 0, stream>>>(dst, E, cnt);
  k_scan1<<<nb_n, 256, 0, stream>>>(cnt, N, partial);
  k_scan3<<<nb_n, 256, 0, stream>>>(cnt, partial, nb_n, N, row_off, cursor, dinv);
  k_place<<<nb_e, 256, 0, stream>>>(src, dst, E, cursor, dinv, edges);

  // ---- weight prep ----
  k_prepW<<<(40960 + 255) / 256, 256, 0, stream>>>(W1, W2, Wl, b1h, b1l, b2h, b2l, blh, bll);

  int gemm_blocks = (N + 127) / 128;
  int agg_blocks = (N + 3) / 4;

  // ---- layer 1 (A = fp32 x, split in-register) ----
  gemm2<8, true, false, true><<<gemm_blocks, 256, 0, stream>>>(x, nullptr, b1h, b1l, nullptr, t_bf, N);
  k_agg<<<agg_blocks, 256, 0, stream>>>(t_bf, row_off, (const int2*)edges, dinv, b1, xh, xl, N);
  // ---- layer 2 ----
  gemm2<8, false, false, true><<<gemm_blocks, 256, 0, stream>>>(xh, xl, b2h, b2l, nullptr, t_bf, N);
  k_agg<<<agg_blocks, 256, 0, stream>>>(t_bf, row_off, (const int2*)edges, dinv, b2, xh, xl, N);
  // ---- classifier ----
  gemm2<4, false, true, false><<<gemm_blocks, 256, 0, stream>>>(xh, xl, blh, bll, bl, out, N);
}

// Round 6
// 246.452 us; speedup vs baseline: 1.7995x; 1.0576x over previous
//
#include <hip/hip_runtime.h>

// -------------------------------------------------------------------------
// GCN: h1 = relu(Agg(x@W1)+b1); h2 = relu(Agg(h1@W2)+b2); out = h2@Wl+bl
// R6: k_agg lanes span 4 edges x 16 lanes x 16B (one VMEM = 4 rows, no
//     serial tail, unroll x2 = 8 rows in flight); GEMM prefetches all A
//     fragments before B LDS staging (pure LDS+MFMA K-loop); prepW fused
//     into scan1 dispatch.
// -------------------------------------------------------------------------

typedef __attribute__((ext_vector_type(8))) __bf16 bf16x8;
typedef __attribute__((ext_vector_type(8))) short short8;
typedef __attribute__((ext_vector_type(4))) float f32x4;

__device__ inline float bf_lo(unsigned u) { return __uint_as_float(u << 16); }
__device__ inline float bf_hi(unsigned u) { return __uint_as_float(u & 0xffff0000u); }
__device__ inline unsigned short f2bf(float v) {
  return __builtin_bit_cast(unsigned short, (__bf16)v);
}

__global__ void k_count(const int* __restrict__ dst, int E, int* __restrict__ cnt) {
  int i = blockIdx.x * blockDim.x + threadIdx.x;
  if (i < E) atomicAdd(&cnt[dst[i]], 1);
}

// fat kernel: blocks [0, nb) do scan1 partials; blocks [nb, nb+160) do prepW
__global__ void k_scan1_prepW(const int* __restrict__ cnt, int n, int* __restrict__ partial,
                              int nb,
                              const float* __restrict__ W1, const float* __restrict__ W2,
                              const float* __restrict__ Wl,
                              unsigned short* __restrict__ b1h, unsigned short* __restrict__ b1l,
                              unsigned short* __restrict__ b2h, unsigned short* __restrict__ b2l,
                              unsigned short* __restrict__ blh, unsigned short* __restrict__ bll) {
  if ((int)blockIdx.x < nb) {
    __shared__ int s[256];
    int i = blockIdx.x * 256 + threadIdx.x;
    s[threadIdx.x] = (i < n) ? cnt[i] : 0;
    __syncthreads();
    for (int off = 128; off > 0; off >>= 1) {
      if (threadIdx.x < off) s[threadIdx.x] += s[threadIdx.x + off];
      __syncthreads();
    }
    if (threadIdx.x == 0) partial[blockIdx.x] = s[0];
  } else {
    int idx = ((int)blockIdx.x - nb) * 256 + threadIdx.x;
    const float* W;
    unsigned short *bh, *bl_;
    int N, local;
    if (idx < 16384)      { W = W1; bh = b1h; bl_ = b1l; N = 128; local = idx; }
    else if (idx < 32768) { W = W2; bh = b2h; bl_ = b2l; N = 128; local = idx - 16384; }
    else if (idx < 40960) { W = Wl; bh = blh; bl_ = bll; N = 64;  local = idx - 32768; }
    else return;
    int nn = local >> 7, k = local & 127;
    float v = W[(size_t)k * N + nn];
    __bf16 h = (__bf16)v;
    bh[local] = __builtin_bit_cast(unsigned short, h);
    bl_[local] = f2bf(v - (float)h);
  }
}

// scan3 with built-in base reduction (no separate scan2 pass)
__global__ void k_scan3(const int* __restrict__ cnt, const int* __restrict__ partial,
                        int nb, int n, int* __restrict__ row_off, int* __restrict__ cursor,
                        float* __restrict__ dinv) {
  __shared__ int s[256];
  __shared__ int base_s;
  int t = threadIdx.x;
  s[t] = (t < nb && t < (int)blockIdx.x) ? partial[t] : 0;
  __syncthreads();
  for (int off = 128; off > 0; off >>= 1) {
    if (t < off) s[t] += s[t + off];
    __syncthreads();
  }
  if (t == 0) base_s = s[0];
  __syncthreads();
  int base = base_s;
  __syncthreads();

  int i = blockIdx.x * 256 + t;
  int v = (i < n) ? cnt[i] : 0;
  s[t] = v;
  __syncthreads();
  for (int off = 1; off < 256; off <<= 1) {
    int u = (t >= off) ? s[t - off] : 0;
    __syncthreads();
    s[t] += u;
    __syncthreads();
  }
  int incl = s[t];
  int excl = incl - v;
  if (i < n) {
    row_off[i] = base + excl;
    cursor[i] = base + excl;
    dinv[i] = rsqrtf((float)(v + 1));
    if (i == n - 1) row_off[n] = base + incl;
  }
}

// packed edge: low32 = src node, high32 = bit-cast norm weight; NT 8B scatter
__global__ void k_place(const int* __restrict__ src, const int* __restrict__ dst, int E,
                        int* __restrict__ cursor, const float* __restrict__ dinv,
                        unsigned long long* __restrict__ edges) {
  int e = blockIdx.x * blockDim.x + threadIdx.x;
  if (e < E) {
    int s = src[e], d = dst[e];
    int pos = atomicAdd(&cursor[d], 1);
    unsigned long long packed =
        (unsigned long long)(unsigned)s |
        ((unsigned long long)__float_as_uint(dinv[s] * dinv[d]) << 32);
    __builtin_nontemporal_store(packed, &edges[pos]);
  }
}

// ------------------- MFMA GEMM v3: A prefetched, B in LDS -------------------
// C[M x N] = A[M x 128] @ B[128 x N] (+bias), N = NT*16.
// All per-wave A fragments loaded up-front (16-32 VMEM in flight), then B
// cooperatively staged (XOR-swizzled), then a pure LDS+MFMA K-loop.
// 3-term split: hi*hi + hi*lo + lo*hi (~2^-17 rel error).
template <int NT, bool A32, bool BIAS, bool OUT_BF16>
__global__ __launch_bounds__(256) void gemm3(
    const void* __restrict__ Ahi_, const unsigned short* __restrict__ Alo,
    const unsigned short* __restrict__ Bhi, const unsigned short* __restrict__ Blo,
    const float* __restrict__ bias, void* __restrict__ Cout, int M) {
  constexpr int K = 128;
  constexpr int NCOL = NT * 16;
  __shared__ alignas(16) unsigned short lbh[NCOL * K];
  __shared__ alignas(16) unsigned short lbl[NCOL * K];
  int t = threadIdx.x;
  int lane = t & 63, wave = t >> 6;
  int lm = lane & 15, lk = lane >> 4;
  int m_base = blockIdx.x * 128 + wave * 32;
  const short8 zero8 = {0, 0, 0, 0, 0, 0, 0, 0};

  // ---- phase 1: prefetch all A fragments ----
  bf16x8 ah[2][4], al[2][4];
  if (A32) {
    const float* Af = (const float*)Ahi_;
    float4 ra[2][4][2];
#pragma unroll
    for (int mt = 0; mt < 2; ++mt) {
      int row = m_base + mt * 16 + lm;
#pragma unroll
      for (int ks = 0; ks < 4; ++ks) {
        if (row < M) {
          ra[mt][ks][0] = *(const float4*)&Af[(size_t)row * K + ks * 32 + lk * 8];
          ra[mt][ks][1] = *(const float4*)&Af[(size_t)row * K + ks * 32 + lk * 8 + 4];
        } else {
          ra[mt][ks][0] = make_float4(0.f, 0.f, 0.f, 0.f);
          ra[mt][ks][1] = make_float4(0.f, 0.f, 0.f, 0.f);
        }
      }
    }
#pragma unroll
    for (int mt = 0; mt < 2; ++mt)
#pragma unroll
      for (int ks = 0; ks < 4; ++ks) {
        float av[8] = {ra[mt][ks][0].x, ra[mt][ks][0].y, ra[mt][ks][0].z, ra[mt][ks][0].w,
                       ra[mt][ks][1].x, ra[mt][ks][1].y, ra[mt][ks][1].z, ra[mt][ks][1].w};
#pragma unroll
        for (int j = 0; j < 8; ++j) {
          __bf16 h = (__bf16)av[j];
          ah[mt][ks][j] = h;
          al[mt][ks][j] = (__bf16)(av[j] - (float)h);
        }
      }
  } else {
    const unsigned short* Ahi = (const unsigned short*)Ahi_;
#pragma unroll
    for (int mt = 0; mt < 2; ++mt) {
      int row = m_base + mt * 16 + lm;
#pragma unroll
      for (int ks = 0; ks < 4; ++ks) {
        if (row < M) {
          ah[mt][ks] = *(const bf16x8*)&Ahi[(size_t)row * K + ks * 32 + lk * 8];
          al[mt][ks] = *(const bf16x8*)&Alo[(size_t)row * K + ks * 32 + lk * 8];
        } else {
          ah[mt][ks] = __builtin_bit_cast(bf16x8, zero8);
          al[mt][ks] = __builtin_bit_cast(bf16x8, zero8);
        }
      }
    }
  }

  // ---- phase 2: cooperative B staging (XOR-swizzled 16B chunks) ----
  for (int c = t; c < NCOL * 16; c += 256) {
    int r = c >> 4, q = c & 15;
    int sq = q ^ (r & 15);
    *(short8*)&lbh[r * K + sq * 8] = *(const short8*)&Bhi[r * K + q * 8];
    *(short8*)&lbl[r * K + sq * 8] = *(const short8*)&Blo[r * K + q * 8];
  }
  __syncthreads();

  // ---- phase 3: pure LDS + MFMA ----
  f32x4 acc[2][NT] = {};
#pragma unroll
  for (int ks = 0; ks < 4; ++ks) {
    int chunk = ks * 4 + lk;
    bf16x8 bh[NT], bl[NT];
#pragma unroll
    for (int nt = 0; nt < NT; ++nt) {
      int r = nt * 16 + lm;
      int sq = chunk ^ lm;
      bh[nt] = *(const bf16x8*)&lbh[r * K + sq * 8];
      bl[nt] = *(const bf16x8*)&lbl[r * K + sq * 8];
    }
#pragma unroll
    for (int mt = 0; mt < 2; ++mt)
#pragma unroll
      for (int nt = 0; nt < NT; ++nt) {
        acc[mt][nt] = __builtin_amdgcn_mfma_f32_16x16x32_bf16(ah[mt][ks], bh[nt], acc[mt][nt], 0, 0, 0);
        acc[mt][nt] = __builtin_amdgcn_mfma_f32_16x16x32_bf16(ah[mt][ks], bl[nt], acc[mt][nt], 0, 0, 0);
        acc[mt][nt] = __builtin_amdgcn_mfma_f32_16x16x32_bf16(al[mt][ks], bh[nt], acc[mt][nt], 0, 0, 0);
      }
  }

  // ---- epilogue: row = lk*4 + r, col = lm within each 16x16 tile ----
#pragma unroll
  for (int mt = 0; mt < 2; ++mt) {
#pragma unroll
    for (int r = 0; r < 4; ++r) {
      int row = m_base + mt * 16 + lk * 4 + r;
      if (row < M) {
#pragma unroll
        for (int nt = 0; nt < NT; ++nt) {
          int col = nt * 16 + lm;
          float v = acc[mt][nt][r];
          if (BIAS) v += bias[col];
          if (OUT_BF16)
            ((unsigned short*)Cout)[(size_t)row * NCOL + col] = f2bf(v);
          else
            __builtin_nontemporal_store(v, &((float*)Cout)[(size_t)row * NCOL + col]);
        }
      }
    }
  }
}

// ------------------- aggregation v3: 4 edges x 16 lanes x 16B -------------------
// one wave per node; lane group g=lane>>4 handles edge (base+g), 16 lanes
// cover the 128 bf16 features (16B each). One VMEM instr = 4 full rows.
// Unroll x2 = 8 rows in flight. OOB edges: clamped index, zero weight.
__global__ __launch_bounds__(256) void k_agg(const unsigned short* __restrict__ t,
                      const int* __restrict__ row_off,
                      const int2* __restrict__ edges,
                      const float* __restrict__ dinv, const float* __restrict__ bias,
                      unsigned short* __restrict__ ghi, unsigned short* __restrict__ glo,
                      int n) {
  int wave = threadIdx.x >> 6;
  int lane = threadIdx.x & 63;
  int g = lane >> 4;
  int fl = lane & 15;          // features fl*8 .. fl*8+7
  int node = blockIdx.x * 4 + wave;
  if (node >= n) return;
  int e0 = row_off[node], e1 = row_off[node + 1];
  int last = e1 - 1;

  float acc[8] = {};
  for (int base = e0; base < e1; base += 8) {
    int i0 = base + g, i1 = base + 4 + g;
    int c0 = i0 < e1 ? i0 : last;
    int c1 = i1 < e1 ? i1 : last;
    int2 p0 = edges[c0];
    int2 p1 = edges[c1];
    uint4 u0 = *(const uint4*)&t[(size_t)p0.x * 128 + fl * 8];
    uint4 u1 = *(const uint4*)&t[(size_t)p1.x * 128 + fl * 8];
    float w0 = i0 < e1 ? __int_as_float(p0.y) : 0.f;
    float w1 = i1 < e1 ? __int_as_float(p1.y) : 0.f;
    acc[0] += w0 * bf_lo(u0.x); acc[1] += w0 * bf_hi(u0.x);
    acc[2] += w0 * bf_lo(u0.y); acc[3] += w0 * bf_hi(u0.y);
    acc[4] += w0 * bf_lo(u0.z); acc[5] += w0 * bf_hi(u0.z);
    acc[6] += w0 * bf_lo(u0.w); acc[7] += w0 * bf_hi(u0.w);
    acc[0] += w1 * bf_lo(u1.x); acc[1] += w1 * bf_hi(u1.x);
    acc[2] += w1 * bf_lo(u1.y); acc[3] += w1 * bf_hi(u1.y);
    acc[4] += w1 * bf_lo(u1.z); acc[5] += w1 * bf_hi(u1.z);
    acc[6] += w1 * bf_lo(u1.w); acc[7] += w1 * bf_hi(u1.w);
  }
#pragma unroll
  for (int j = 0; j < 8; ++j) {
    acc[j] += __shfl_xor(acc[j], 16);
    acc[j] += __shfl_xor(acc[j], 32);
  }
  if (g == 0) {
    float di = dinv[node];
    float self = di * di;
    uint4 sv = *(const uint4*)&t[(size_t)node * 128 + fl * 8];
    acc[0] += self * bf_lo(sv.x); acc[1] += self * bf_hi(sv.x);
    acc[2] += self * bf_lo(sv.y); acc[3] += self * bf_hi(sv.y);
    acc[4] += self * bf_lo(sv.z); acc[5] += self * bf_hi(sv.z);
    acc[6] += self * bf_lo(sv.w); acc[7] += self * bf_hi(sv.w);
    float4 bb0 = *(const float4*)&bias[fl * 8];
    float4 bb1 = *(const float4*)&bias[fl * 8 + 4];
    float bb[8] = {bb0.x, bb0.y, bb0.z, bb0.w, bb1.x, bb1.y, bb1.z, bb1.w};
    short8 ho, lo_;
#pragma unroll
    for (int j = 0; j < 8; ++j) {
      float s = fmaxf(acc[j] + bb[j], 0.f);
      __bf16 h = (__bf16)s;
      ho[j] = __builtin_bit_cast(short, h);
      lo_[j] = (short)f2bf(s - (float)h);
    }
    *(short8*)&ghi[(size_t)node * 128 + fl * 8] = ho;
    *(short8*)&glo[(size_t)node * 128 + fl * 8] = lo_;
  }
}

extern "C" void kernel_launch(void* const* d_in, const int* in_sizes, int n_in,
                              void* d_out, int out_size, void* d_ws, size_t ws_size,
                              hipStream_t stream) {
  const float* x  = (const float*)d_in[0];
  const int*   ei = (const int*)d_in[1];
  const float* W1 = (const float*)d_in[2];
  const float* b1 = (const float*)d_in[3];
  const float* W2 = (const float*)d_in[4];
  const float* b2 = (const float*)d_in[5];
  const float* Wl = (const float*)d_in[6];
  const float* bl = (const float*)d_in[7];
  float* out = (float*)d_out;

  const int D = 128;
  int N = in_sizes[0] / D;
  int E = in_sizes[1] / 2;
  const int* src = ei;
  const int* dst = ei + E;

  uintptr_t ws = (uintptr_t)d_ws;
  auto take = [&](size_t bytes) {
    uintptr_t p = ws;
    ws += (bytes + 15) & ~(size_t)15;
    return p;
  };
  unsigned short* t_bf = (unsigned short*)take((size_t)N * D * 2);  // bf16 GEMM out
  unsigned short* xh   = (unsigned short*)take((size_t)N * D * 2);  // agg out hi
  unsigned short* xl   = (unsigned short*)take((size_t)N * D * 2);  // agg out lo
  unsigned long long* edges = (unsigned long long*)take((size_t)E * 8);
  int*   cnt     = (int*)take((size_t)N * sizeof(int));
  int*   row_off = (int*)take(((size_t)N + 1) * sizeof(int));
  int*   cursor  = (int*)take((size_t)N * sizeof(int));
  float* dinv    = (float*)take((size_t)N * sizeof(float));
  int*   partial = (int*)take(256 * sizeof(int));
  unsigned short* b1h = (unsigned short*)take(128 * 128 * 2);
  unsigned short* b1l = (unsigned short*)take(128 * 128 * 2);
  unsigned short* b2h = (unsigned short*)take(128 * 128 * 2);
  unsigned short* b2l = (unsigned short*)take(128 * 128 * 2);
  unsigned short* blh = (unsigned short*)take(128 * 64 * 2);
  unsigned short* bll = (unsigned short*)take(128 * 64 * 2);

  int nb_n = (N + 255) / 256;   // 196 for N=50000 (single-block base reduce ok)
  int nb_e = (E + 255) / 256;

  // ---- graph preprocessing + weight prep ----
  hipMemsetAsync(cnt, 0, (size_t)N * sizeof(int), stream);
  k_count<<<nb_e, 256, 0, stream>>>(dst, E, cnt);
  k_scan1_prepW<<<nb_n + 160, 256, 0, stream>>>(cnt, N, partial, nb_n,
                                                W1, W2, Wl, b1h, b1l, b2h, b2l, blh, bll);
  k_scan3<<<nb_n, 256, 0, stream>>>(cnt, partial, nb_n, N, row_off, cursor, dinv);
  k_place<<<nb_e, 256, 0, stream>>>(src, dst, E, cursor, dinv, edges);

  int gemm_blocks = (N + 127) / 128;
  int agg_blocks = (N + 3) / 4;

  // ---- layer 1 (A = fp32 x, split in-register) ----
  gemm3<8, true, false, true><<<gemm_blocks, 256, 0, stream>>>(x, nullptr, b1h, b1l, nullptr, t_bf, N);
  k_agg<<<agg_blocks, 256, 0, stream>>>(t_bf, row_off, (const int2*)edges, dinv, b1, xh, xl, N);
  // ---- layer 2 ----
  gemm3<8, false, false, true><<<gemm_blocks, 256, 0, stream>>>(xh, xl, b2h, b2l, nullptr, t_bf, N);
  k_agg<<<agg_blocks, 256, 0, stream>>>(t_bf, row_off, (const int2*)edges, dinv, b2, xh, xl, N);
  // ---- classifier ----
  gemm3<4, false, true, false><<<gemm_blocks, 256, 0, stream>>>(xh, xl, blh, bll, bl, out, N);
}